// Round 2
// baseline (385.441 us; speedup 1.0000x reference)
//
#include <hip/hip_runtime.h>
#include <hip/hip_bf16.h>
#include <stdint.h>

#define NROWS      65536
#define RPB        32
#define NBLK       (NROWS/RPB)      // 2048
#define H2N        100
#define KPAD       128
#define N3         1224
#define NPAD       1232             // 77 tiles of 16
#define NTILES     77
#define OUTW       2193
#define NJ         57
#define TAILN      (NJ*17)          // 969

typedef __attribute__((ext_vector_type(8))) short bf16x8;
typedef __attribute__((ext_vector_type(4))) float f32x4;

__device__ __forceinline__ float fast_sigmoid(float z){
    return __builtin_amdgcn_rcpf(1.0f + __expf(-z));
}

__device__ __forceinline__ unsigned short f2bf(float v){
    __hip_bfloat16 h = __float2bfloat16(v);
    return *reinterpret_cast<unsigned short*>(&h);
}

// blocks 0..615: W3 (100 x 1224 f32) -> w3t[col][k] bf16 zero-padded [1232][128]
// blocks 616+ : tail constants  pk[p] = (c2<<16)|c1,  pw[p] = w[j]
__global__ void prep_kernel(const float* __restrict__ W3,
                            const float* __restrict__ wgt,
                            const int* __restrict__ idx1,
                            const int* __restrict__ idx2,
                            unsigned short* __restrict__ w3t,
                            unsigned int* __restrict__ pk,
                            float* __restrict__ pw){
    int idx = blockIdx.x * 256 + threadIdx.x;
    if (idx < NPAD * KPAD){
        int c = idx >> 7;
        int k = idx & 127;
        float v = (k < H2N && c < N3) ? W3[k * N3 + c] : 0.0f;
        w3t[idx] = f2bf(v);
    }
    int p = idx - NPAD * KPAD;
    if (p >= 0 && p < TAILN){
        int j = p / 17, k = p - j * 17;
        unsigned int c1 = (unsigned)(idx1[j] * 17 + k);
        unsigned int c2 = (unsigned)(idx2[j] * 17 + k);
        pk[p] = (c2 << 16) | c1;
        pw[p] = wgt[j];
    }
}

__global__ __launch_bounds__(256, 4)
void snn_kernel(const float* __restrict__ x,
                const float* __restrict__ W1, const float* __restrict__ b1,
                const float* __restrict__ W2, const float* __restrict__ b2,
                const float* __restrict__ b3,
                const unsigned short* __restrict__ w3t,
                const unsigned int* __restrict__ pk,
                const float* __restrict__ pw,
                float* __restrict__ out)
{
    __shared__ __align__(16) unsigned short lds_h2[RPB][KPAD];   // 8 KB
    __shared__ float lds_h1[RPB][10];                            // 1.25 KB

    const int t    = threadIdx.x;
    const int row0 = blockIdx.x * RPB;

    // ---- tail constants straight into registers (L2-resident)
    unsigned int tc[4]; float tw[4];
    #pragma unroll
    for (int i = 0; i < 4; ++i){
        int p = t + i * 256;
        if (p < TAILN){ tc[i] = pk[p]; tw[i] = pw[p]; }
        else          { tc[i] = 0;     tw[i] = 0.0f;  }
    }

    // ---- layer 1 (fp32): h1[r][j], 32 rows x 10
    for (int i = t; i < RPB * 10; i += 256){
        int r = i / 10, j = i - r * 10;
        lds_h1[r][j] = fast_sigmoid(x[row0 + r] * W1[j] + b1[j]);
    }
    __syncthreads();

    // ---- layer 2 (fp32 -> bf16 LDS, zero-pad k=100..127)
    // i = r*128 + c: consecutive threads -> consecutive c (conflict-free b16 writes)
    for (int i = t; i < RPB * KPAD; i += 256){
        int r = i >> 7, c = i & 127;
        float v = 0.0f;
        if (c < H2N){
            float z = b2[c];
            #pragma unroll
            for (int j = 0; j < 10; ++j) z += lds_h1[r][j] * W2[j * H2N + c];
            v = fast_sigmoid(z);
        }
        lds_h2[r][c] = f2bf(v);
    }
    __syncthreads();

    // ---- layer 3 via MFMA 16x16x32 bf16, K = 128 (4 k-steps), store direct to out
    const int lane = t & 63, wid = t >> 6;
    const int rt = wid >> 1, par = wid & 1;   // row-tile 0/1, n-parity 0/1
    const int lm = lane & 15, lg = lane >> 4;

    bf16x8 afr[4];
    #pragma unroll
    for (int ks = 0; ks < 4; ++ks)
        afr[ks] = *reinterpret_cast<const bf16x8*>(&lds_h2[rt * 16 + lm][ks * 32 + lg * 8]);

    for (int nt = par; nt < NTILES; nt += 2){
        const int c0 = nt * 16 + lm;
        const unsigned short* bp = w3t + (size_t)c0 * KPAD + lg * 8;
        bf16x8 bfr[4];
        #pragma unroll
        for (int ks = 0; ks < 4; ++ks)
            bfr[ks] = *reinterpret_cast<const bf16x8*>(bp + ks * 32);

        f32x4 acc = {0.0f, 0.0f, 0.0f, 0.0f};
        #pragma unroll
        for (int ks = 0; ks < 4; ++ks)
            acc = __builtin_amdgcn_mfma_f32_16x16x32_bf16(afr[ks], bfr[ks], acc, 0, 0, 0);

        if (c0 < N3){
            const float b3v = b3[c0];
            const int   lrow = rt * 16 + lg * 4;
            #pragma unroll
            for (int r = 0; r < 4; ++r){
                float h = fast_sigmoid(acc[r] + b3v);
                out[(size_t)(row0 + lrow + r) * OUTW + c0] = h;   // D: row=lg*4+r, col=lm
            }
        }
    }
    __syncthreads();

    // ---- tail: read h3 back from out (L2-hot), lerp, coalesced stores
    #pragma unroll 2
    for (int r = 0; r < RPB; ++r){
        const float* orow = out + (size_t)(row0 + r) * OUTW;
        float*       trow = (float*)orow + N3;
        #pragma unroll
        for (int i = 0; i < 4; ++i){
            int p = t + i * 256;
            if (p < TAILN){
                int c1 = (int)(tc[i] & 0xffffu);
                int c2 = (int)(tc[i] >> 16);
                float v1 = orow[c1];
                float v2 = orow[c2];
                trow[p] = fmaf(tw[i], v1 - v2, v2);   // w*v1 + (1-w)*v2
            }
        }
    }
}

extern "C" void kernel_launch(void* const* d_in, const int* in_sizes, int n_in,
                              void* d_out, int out_size, void* d_ws, size_t ws_size,
                              hipStream_t stream)
{
    const float* x   = (const float*)d_in[0];
    const float* W1  = (const float*)d_in[1];
    const float* b1  = (const float*)d_in[2];
    const float* W2  = (const float*)d_in[3];
    const float* b2  = (const float*)d_in[4];
    const float* W3  = (const float*)d_in[5];
    const float* b3  = (const float*)d_in[6];
    const float* wgt = (const float*)d_in[7];
    const int*   i1  = (const int*)d_in[8];
    const int*   i2  = (const int*)d_in[9];
    float* out = (float*)d_out;

    unsigned char* ws = (unsigned char*)d_ws;
    unsigned short* w3t = (unsigned short*)ws;                       // 315,392 B
    unsigned int*   pk  = (unsigned int*)(ws + 315392);              // 3,876 B
    float*          pw  = (float*)(ws + 315392 + 3904);              // 3,876 B

    const int prep_blocks = (NPAD * KPAD + TAILN + 255) / 256;       // 620
    prep_kernel<<<prep_blocks, 256, 0, stream>>>(W3, wgt, i1, i2, w3t, pk, pw);
    snn_kernel<<<NBLK, 256, 0, stream>>>(x, W1, b1, W2, b2, b3, w3t, pk, pw, out);
}

// Round 3
// 301.428 us; speedup vs baseline: 1.2787x; 1.2787x over previous
//
#include <hip/hip_runtime.h>
#include <hip/hip_bf16.h>
#include <stdint.h>

#define NROWS   65536
#define RPB     32
#define NBLK    (NROWS/RPB)       // 2048
#define H2N     100
#define KPAD    128
#define N3      1224
#define OUTW    2193
#define NMAIN   77                // main n-tiles (1232 cols padded)
#define NPAIR   61                // pair tiles per side (976 cols padded)
#define T1OFF   77                // tiles holding h3[c1[p]]
#define T2OFF   138               // tiles holding h3[c2[p]]
#define NTOT    199               // total tiles
#define TAILN   969

typedef __attribute__((ext_vector_type(8))) short bf16x8;
typedef __attribute__((ext_vector_type(4))) float f32x4;

__device__ __forceinline__ float fast_sigmoid(float z){
    return __builtin_amdgcn_rcpf(1.0f + __expf(-z));
}
__device__ __forceinline__ unsigned short f2bf(float v){
    __hip_bfloat16 h = __float2bfloat16(v);
    return *reinterpret_cast<unsigned short*>(&h);
}

// Build fragment-ordered extended B: w3f[((t*4+ks)*64+lane)*8 + e]
//   = bf16( W3[k=ks*32+(lane>>4)*8+e][ srccol(t, lane&15) ] ), zero-padded.
// Tiles: t<77 -> col=t*16+lm (if <1224); 77<=t<138 -> col=c1[p]; 138<=t<199 -> col=c2[p],
// where p=(t-off)*16+lm, c1[p]=idx1[p/17]*17+p%17, etc.
// Also b3f[t*16+lm]=b3[srccol] (0 if pad), pwf[p]=wgt[p/17].
__global__ void prep_kernel(const float* __restrict__ W3,
                            const float* __restrict__ b3,
                            const float* __restrict__ wgt,
                            const int* __restrict__ idx1,
                            const int* __restrict__ idx2,
                            unsigned short* __restrict__ w3f,
                            float* __restrict__ b3f,
                            float* __restrict__ pwf){
    const int t    = blockIdx.x;            // one tile per block
    const int ks   = threadIdx.x >> 6;
    const int lane = threadIdx.x & 63;
    const int lm   = lane & 15, lg = lane >> 4;

    int col = -1;
    if (t < T1OFF){
        int c = t * 16 + lm;
        if (c < N3) col = c;
    } else if (t < T2OFF){
        int p = (t - T1OFF) * 16 + lm;
        if (p < TAILN){ int j = p / 17; col = idx1[j] * 17 + (p - j * 17); }
    } else {
        int p = (t - T2OFF) * 16 + lm;
        if (p < TAILN){ int j = p / 17; col = idx2[j] * 17 + (p - j * 17); }
    }

    unsigned short vals[8];
    #pragma unroll
    for (int e = 0; e < 8; ++e){
        int k = ks * 32 + lg * 8 + e;
        float v = (col >= 0 && k < H2N) ? W3[k * N3 + col] : 0.0f;
        vals[e] = f2bf(v);
    }
    *reinterpret_cast<bf16x8*>(w3f + ((size_t)(t * 4 + ks) * 64 + lane) * 8)
        = *reinterpret_cast<bf16x8*>(vals);

    if (ks == 0 && lg == 0)
        b3f[t * 16 + lm] = (col >= 0) ? b3[col] : 0.0f;
    if (ks == 0 && lg == 1 && t >= T1OFF && t < T2OFF){
        int p = (t - T1OFF) * 16 + lm;
        if (p < TAILN) pwf[p] = wgt[p / 17];
    }
}

__global__ __launch_bounds__(256, 5)
void snn_kernel(const float* __restrict__ x,
                const float* __restrict__ W1, const float* __restrict__ b1,
                const float* __restrict__ W2, const float* __restrict__ b2,
                const unsigned short* __restrict__ w3f,
                const float* __restrict__ b3f,
                const float* __restrict__ pwf,
                float* __restrict__ out)
{
    __shared__ __align__(16) unsigned short lds_h2[RPB][KPAD];   // 8 KB
    __shared__ float lds_h1[RPB][10];                            // 1.25 KB

    const int t    = threadIdx.x;
    const int row0 = blockIdx.x * RPB;

    // ---- layer 1
    for (int i = t; i < RPB * 10; i += 256){
        int r = i / 10, j = i - r * 10;
        lds_h1[r][j] = fast_sigmoid(x[row0 + r] * W1[j] + b1[j]);
    }
    __syncthreads();

    // ---- layer 2 -> bf16 LDS (consecutive threads -> consecutive c: conflict-free)
    for (int i = t; i < RPB * KPAD; i += 256){
        int r = i >> 7, c = i & 127;
        float v = 0.0f;
        if (c < H2N){
            float z = b2[c];
            #pragma unroll
            for (int j = 0; j < 10; ++j) z += lds_h1[r][j] * W2[j * H2N + c];
            v = fast_sigmoid(z);
        }
        lds_h2[r][c] = f2bf(v);
    }
    __syncthreads();

    // ---- layer 3 + tail, single MFMA sweep; each wave serves BOTH row-tiles
    const int lane = t & 63, wid = t >> 6;
    const int lm = lane & 15, lg = lane >> 4;

    bf16x8 afr[2][4];
    #pragma unroll
    for (int rt = 0; rt < 2; ++rt)
        #pragma unroll
        for (int ks = 0; ks < 4; ++ks)
            afr[rt][ks] = *reinterpret_cast<const bf16x8*>(&lds_h2[rt * 16 + lm][ks * 32 + lg * 8]);

    const size_t r0 = (size_t)(row0 + lg * 4) * OUTW;        // rt=0 base
    const size_t r1 = (size_t)(row0 + 16 + lg * 4) * OUTW;   // rt=1 base

    // main tiles: cols 0..1223
    for (int nt = wid; nt < NMAIN; nt += 4){
        const unsigned short* bp = w3f + ((size_t)(nt * 4) * 64 + lane) * 8;
        bf16x8 bfr[4];
        #pragma unroll
        for (int ks = 0; ks < 4; ++ks)
            bfr[ks] = *reinterpret_cast<const bf16x8*>(bp + (size_t)ks * 512);
        f32x4 a0 = {0,0,0,0}, a1 = {0,0,0,0};
        #pragma unroll
        for (int ks = 0; ks < 4; ++ks){
            a0 = __builtin_amdgcn_mfma_f32_16x16x32_bf16(afr[0][ks], bfr[ks], a0, 0, 0, 0);
            a1 = __builtin_amdgcn_mfma_f32_16x16x32_bf16(afr[1][ks], bfr[ks], a1, 0, 0, 0);
        }
        const int c0 = nt * 16 + lm;
        if (c0 < N3){
            const float b3v = b3f[c0];
            #pragma unroll
            for (int r = 0; r < 4; ++r){
                out[r0 + (size_t)r * OUTW + c0] = fast_sigmoid(a0[r] + b3v);
                out[r1 + (size_t)r * OUTW + c0] = fast_sigmoid(a1[r] + b3v);
            }
        }
    }

    // pair tiles: tail = w*u1 + (1-w)*u2, computed fresh from gathered W3 columns
    for (int i = wid; i < NPAIR; i += 4){
        const unsigned short* bp1 = w3f + ((size_t)((T1OFF + i) * 4) * 64 + lane) * 8;
        const unsigned short* bp2 = w3f + ((size_t)((T2OFF + i) * 4) * 64 + lane) * 8;
        f32x4 a10 = {0,0,0,0}, a11 = {0,0,0,0};
        #pragma unroll
        for (int ks = 0; ks < 4; ++ks){
            bf16x8 bv = *reinterpret_cast<const bf16x8*>(bp1 + (size_t)ks * 512);
            a10 = __builtin_amdgcn_mfma_f32_16x16x32_bf16(afr[0][ks], bv, a10, 0, 0, 0);
            a11 = __builtin_amdgcn_mfma_f32_16x16x32_bf16(afr[1][ks], bv, a11, 0, 0, 0);
        }
        f32x4 a20 = {0,0,0,0}, a21 = {0,0,0,0};
        #pragma unroll
        for (int ks = 0; ks < 4; ++ks){
            bf16x8 bv = *reinterpret_cast<const bf16x8*>(bp2 + (size_t)ks * 512);
            a20 = __builtin_amdgcn_mfma_f32_16x16x32_bf16(afr[0][ks], bv, a20, 0, 0, 0);
            a21 = __builtin_amdgcn_mfma_f32_16x16x32_bf16(afr[1][ks], bv, a21, 0, 0, 0);
        }
        const int p = i * 16 + lm;
        if (p < TAILN){
            const float bv1 = b3f[(T1OFF + i) * 16 + lm];
            const float bv2 = b3f[(T2OFF + i) * 16 + lm];
            const float wv  = pwf[p];
            #pragma unroll
            for (int r = 0; r < 4; ++r){
                float u1 = fast_sigmoid(a10[r] + bv1);
                float u2 = fast_sigmoid(a20[r] + bv2);
                out[r0 + (size_t)r * OUTW + N3 + p] = fmaf(wv, u1 - u2, u2);
                u1 = fast_sigmoid(a11[r] + bv1);
                u2 = fast_sigmoid(a21[r] + bv2);
                out[r1 + (size_t)r * OUTW + N3 + p] = fmaf(wv, u1 - u2, u2);
            }
        }
    }
}

extern "C" void kernel_launch(void* const* d_in, const int* in_sizes, int n_in,
                              void* d_out, int out_size, void* d_ws, size_t ws_size,
                              hipStream_t stream)
{
    const float* x   = (const float*)d_in[0];
    const float* W1  = (const float*)d_in[1];
    const float* b1  = (const float*)d_in[2];
    const float* W2  = (const float*)d_in[3];
    const float* b2  = (const float*)d_in[4];
    const float* W3  = (const float*)d_in[5];
    const float* b3  = (const float*)d_in[6];
    const float* wgt = (const float*)d_in[7];
    const int*   i1  = (const int*)d_in[8];
    const int*   i2  = (const int*)d_in[9];
    float* out = (float*)d_out;

    unsigned char* ws = (unsigned char*)d_ws;
    unsigned short* w3f = (unsigned short*)ws;                 // 199*4*64*8*2 = 815,104 B
    float*          b3f = (float*)(ws + 815104);               // 3184*4 = 12,736 B
    float*          pwf = (float*)(ws + 815104 + 12736);       // 976*4  =  3,904 B

    prep_kernel<<<NTOT, 256, 0, stream>>>(W3, b3, wgt, i1, i2, w3f, b3f, pwf);
    snn_kernel<<<NBLK, 256, 0, stream>>>(x, W1, b1, W2, b2, w3f, b3f, pwf, out);
}

// Round 4
// 273.877 us; speedup vs baseline: 1.4074x; 1.1006x over previous
//
#include <hip/hip_runtime.h>
#include <hip/hip_bf16.h>
#include <stdint.h>

#define NROWS   65536
#define RPB     32
#define NBLK    (NROWS/RPB)       // 2048
#define H2N     100
#define KPAD    128
#define N3      1224
#define OUTW    2193
#define NMAIN   77                // main n-tiles (1232 cols padded)
#define NPAIR   61                // pair tiles per side (976 cols padded)
#define T1OFF   77                // tiles holding h3[c1[p]]
#define T2OFF   138               // tiles holding h3[c2[p]]
#define NTOT    199               // total tiles
#define TAILN   969

typedef __attribute__((ext_vector_type(8))) short bf16x8;
typedef __attribute__((ext_vector_type(4))) float f32x4;

__device__ __forceinline__ float fast_sigmoid(float z){
    return __builtin_amdgcn_rcpf(1.0f + __expf(-z));
}
__device__ __forceinline__ unsigned short f2bf(float v){
    __hip_bfloat16 h = __float2bfloat16(v);
    return *reinterpret_cast<unsigned short*>(&h);
}
// 16B store; out rows are only 4B-aligned (OUTW=2193), gfx950 handles unaligned dwordx4
__device__ __forceinline__ void store16(float* p, f32x4 v){
    __builtin_memcpy(p, &v, 16);
}

// Build fragment-ordered extended B: w3f[((t*4+ks)*64+lane)*8 + e]
//   = bf16( W3[k=ks*32+(lane>>4)*8+e][ srccol(t, lane&15) ] ), zero-padded.
__global__ void prep_kernel(const float* __restrict__ W3,
                            const float* __restrict__ b3,
                            const float* __restrict__ wgt,
                            const int* __restrict__ idx1,
                            const int* __restrict__ idx2,
                            unsigned short* __restrict__ w3f,
                            float* __restrict__ b3f,
                            float* __restrict__ pwf){
    const int t    = blockIdx.x;            // one tile per block
    const int ks   = threadIdx.x >> 6;
    const int lane = threadIdx.x & 63;
    const int lm   = lane & 15, lg = lane >> 4;

    int col = -1;
    if (t < T1OFF){
        int c = t * 16 + lm;
        if (c < N3) col = c;
    } else if (t < T2OFF){
        int p = (t - T1OFF) * 16 + lm;
        if (p < TAILN){ int j = p / 17; col = idx1[j] * 17 + (p - j * 17); }
    } else {
        int p = (t - T2OFF) * 16 + lm;
        if (p < TAILN){ int j = p / 17; col = idx2[j] * 17 + (p - j * 17); }
    }

    unsigned short vals[8];
    #pragma unroll
    for (int e = 0; e < 8; ++e){
        int k = ks * 32 + lg * 8 + e;
        float v = (col >= 0 && k < H2N) ? W3[k * N3 + col] : 0.0f;
        vals[e] = f2bf(v);
    }
    *reinterpret_cast<bf16x8*>(w3f + ((size_t)(t * 4 + ks) * 64 + lane) * 8)
        = *reinterpret_cast<bf16x8*>(vals);

    if (ks == 0 && lg == 0)
        b3f[t * 16 + lm] = (col >= 0) ? b3[col] : 0.0f;
    if (ks == 0 && lg == 1 && t >= T1OFF && t < T2OFF){
        int p = (t - T1OFF) * 16 + lm;
        if (p < TAILN) pwf[p] = wgt[p / 17];
    }
}

__global__ __launch_bounds__(256, 4)
void snn_kernel(const float* __restrict__ x,
                const float* __restrict__ W1, const float* __restrict__ b1,
                const float* __restrict__ W2, const float* __restrict__ b2,
                const unsigned short* __restrict__ w3f,
                const float* __restrict__ b3f,
                const float* __restrict__ pwf,
                float* __restrict__ out)
{
    __shared__ __align__(16) unsigned short lds_h2[RPB][KPAD];   // 8 KB
    __shared__ float lds_h1[RPB][10];                            // 1.25 KB

    const int t    = threadIdx.x;
    const int row0 = blockIdx.x * RPB;

    // ---- layer 1
    for (int i = t; i < RPB * 10; i += 256){
        int r = i / 10, j = i - r * 10;
        lds_h1[r][j] = fast_sigmoid(x[row0 + r] * W1[j] + b1[j]);
    }
    __syncthreads();

    // ---- layer 2 -> bf16 LDS
    for (int i = t; i < RPB * KPAD; i += 256){
        int r = i >> 7, c = i & 127;
        float v = 0.0f;
        if (c < H2N){
            float z = b2[c];
            #pragma unroll
            for (int j = 0; j < 10; ++j) z += lds_h1[r][j] * W2[j * H2N + c];
            v = fast_sigmoid(z);
        }
        lds_h2[r][c] = f2bf(v);
    }
    __syncthreads();

    // ---- layer 3 + tail: A = W3-tile (rows = out cols), B = h2 (cols = out rows)
    // D layout: out row = row0 + rt*16 + (lane&15); out cols = tile*16 + (lane>>4)*4 + reg
    const int lane = t & 63, wid = t >> 6;
    const int lm = lane & 15, lg = lane >> 4;

    bf16x8 hfr[2][4];   // h2 fragments (B operand), both row-tiles
    #pragma unroll
    for (int rt = 0; rt < 2; ++rt)
        #pragma unroll
        for (int ks = 0; ks < 4; ++ks)
            hfr[rt][ks] = *reinterpret_cast<const bf16x8*>(&lds_h2[rt * 16 + lm][ks * 32 + lg * 8]);

    const size_t r0row = (size_t)(row0 + lm) * OUTW;        // rt=0 row
    const size_t r1row = (size_t)(row0 + 16 + lm) * OUTW;   // rt=1 row

    #define LOADFRAG(dst, tile) do {                                            \
        const unsigned short* bp_ = w3f + ((size_t)((tile) * 4) * 64 + lane) * 8; \
        _Pragma("unroll")                                                        \
        for (int ks_ = 0; ks_ < 4; ++ks_)                                        \
            dst[ks_] = *reinterpret_cast<const bf16x8*>(bp_ + (size_t)ks_ * 512);\
    } while(0)

    // ===== main tiles: cols 0..1223, double-buffered W3 frags =====
    {
        bf16x8 cw[4], nw[4];
        if (wid < NMAIN) LOADFRAG(cw, wid);
        for (int nt = wid; nt < NMAIN; nt += 4){
            const int ntn = nt + 4;
            if (ntn < NMAIN) LOADFRAG(nw, ntn);

            f32x4 a0 = {0,0,0,0}, a1 = {0,0,0,0};
            #pragma unroll
            for (int ks = 0; ks < 4; ++ks){
                a0 = __builtin_amdgcn_mfma_f32_16x16x32_bf16(cw[ks], hfr[0][ks], a0, 0, 0, 0);
                a1 = __builtin_amdgcn_mfma_f32_16x16x32_bf16(cw[ks], hfr[1][ks], a1, 0, 0, 0);
            }

            const int cb = nt * 16 + lg * 4;
            const f32x4 b3v = *reinterpret_cast<const f32x4*>(b3f + cb);
            if (cb + 3 < N3){
                f32x4 v0, v1;
                #pragma unroll
                for (int r = 0; r < 4; ++r){
                    v0[r] = fast_sigmoid(a0[r] + b3v[r]);
                    v1[r] = fast_sigmoid(a1[r] + b3v[r]);
                }
                store16(out + r0row + cb, v0);
                store16(out + r1row + cb, v1);
            } else if (cb < N3){
                #pragma unroll
                for (int r = 0; r < 4; ++r){
                    if (cb + r < N3){
                        out[r0row + cb + r] = fast_sigmoid(a0[r] + b3v[r]);
                        out[r1row + cb + r] = fast_sigmoid(a1[r] + b3v[r]);
                    }
                }
            }
            if (ntn < NMAIN){
                #pragma unroll
                for (int ks = 0; ks < 4; ++ks) cw[ks] = nw[ks];
            }
        }
    }

    // ===== pair tiles: tail = w*sig(u1) + (1-w)*sig(u2), side1 double-buffered =====
    {
        bf16x8 c1f[4], n1f[4];
        if (wid < NPAIR) LOADFRAG(c1f, T1OFF + wid);
        for (int i = wid; i < NPAIR; i += 4){
            bf16x8 c2f[4];
            LOADFRAG(c2f, T2OFF + i);
            const int inext = i + 4;
            if (inext < NPAIR) LOADFRAG(n1f, T1OFF + inext);

            f32x4 a10 = {0,0,0,0}, a11 = {0,0,0,0};
            #pragma unroll
            for (int ks = 0; ks < 4; ++ks){
                a10 = __builtin_amdgcn_mfma_f32_16x16x32_bf16(c1f[ks], hfr[0][ks], a10, 0, 0, 0);
                a11 = __builtin_amdgcn_mfma_f32_16x16x32_bf16(c1f[ks], hfr[1][ks], a11, 0, 0, 0);
            }
            f32x4 a20 = {0,0,0,0}, a21 = {0,0,0,0};
            #pragma unroll
            for (int ks = 0; ks < 4; ++ks){
                a20 = __builtin_amdgcn_mfma_f32_16x16x32_bf16(c2f[ks], hfr[0][ks], a20, 0, 0, 0);
                a21 = __builtin_amdgcn_mfma_f32_16x16x32_bf16(c2f[ks], hfr[1][ks], a21, 0, 0, 0);
            }

            const int pb = i * 16 + lg * 4;
            const f32x4 bv1 = *reinterpret_cast<const f32x4*>(b3f + (T1OFF + i) * 16 + lg * 4);
            const f32x4 bv2 = *reinterpret_cast<const f32x4*>(b3f + (T2OFF + i) * 16 + lg * 4);
            if (pb + 3 < TAILN){
                const f32x4 wv = *reinterpret_cast<const f32x4*>(pwf + pb);
                f32x4 v0, v1;
                #pragma unroll
                for (int r = 0; r < 4; ++r){
                    float u1 = fast_sigmoid(a10[r] + bv1[r]);
                    float u2 = fast_sigmoid(a20[r] + bv2[r]);
                    v0[r] = fmaf(wv[r], u1 - u2, u2);
                    u1 = fast_sigmoid(a11[r] + bv1[r]);
                    u2 = fast_sigmoid(a21[r] + bv2[r]);
                    v1[r] = fmaf(wv[r], u1 - u2, u2);
                }
                store16(out + r0row + N3 + pb, v0);
                store16(out + r1row + N3 + pb, v1);
            } else if (pb < TAILN){
                #pragma unroll
                for (int r = 0; r < 4; ++r){
                    const int p = pb + r;
                    if (p < TAILN){
                        const float wvs = pwf[p];
                        float u1 = fast_sigmoid(a10[r] + bv1[r]);
                        float u2 = fast_sigmoid(a20[r] + bv2[r]);
                        out[r0row + N3 + p] = fmaf(wvs, u1 - u2, u2);
                        u1 = fast_sigmoid(a11[r] + bv1[r]);
                        u2 = fast_sigmoid(a21[r] + bv2[r]);
                        out[r1row + N3 + p] = fmaf(wvs, u1 - u2, u2);
                    }
                }
            }
            if (inext < NPAIR){
                #pragma unroll
                for (int ks = 0; ks < 4; ++ks) c1f[ks] = n1f[ks];
            }
        }
    }
    #undef LOADFRAG
}

extern "C" void kernel_launch(void* const* d_in, const int* in_sizes, int n_in,
                              void* d_out, int out_size, void* d_ws, size_t ws_size,
                              hipStream_t stream)
{
    const float* x   = (const float*)d_in[0];
    const float* W1  = (const float*)d_in[1];
    const float* b1  = (const float*)d_in[2];
    const float* W2  = (const float*)d_in[3];
    const float* b2  = (const float*)d_in[4];
    const float* W3  = (const float*)d_in[5];
    const float* b3  = (const float*)d_in[6];
    const float* wgt = (const float*)d_in[7];
    const int*   i1  = (const int*)d_in[8];
    const int*   i2  = (const int*)d_in[9];
    float* out = (float*)d_out;

    unsigned char* ws = (unsigned char*)d_ws;
    unsigned short* w3f = (unsigned short*)ws;                 // 199*4*64*8*2 = 815,104 B
    float*          b3f = (float*)(ws + 815104);               // 3184*4 = 12,736 B
    float*          pwf = (float*)(ws + 815104 + 12736);       // 976*4  =  3,904 B

    prep_kernel<<<NTOT, 256, 0, stream>>>(W3, b3, wgt, i1, i2, w3f, b3f, pwf);
    snn_kernel<<<NBLK, 256, 0, stream>>>(x, W1, b1, W2, b2, w3f, b3f, pwf, out);
}